// Round 4
// baseline (3434.312 us; speedup 1.0000x reference)
//
#include <hip/hip_runtime.h>
#include <hip/hip_bf16.h>

#define N_NODES 50000
#define DEG     16
#define IN_CH   128
#define TYPE_DIM 32
#define F_DIM   160      // = IN_CH + TYPE_DIM
#define H_DIM   160
#define OUT_CH  128
#define NSTEP   16       // = DEG timesteps
#define LS      168      // LDS row stride in ushorts (16B-aligned; 2-way bank alias only = free)

typedef short  bf16x8 __attribute__((ext_vector_type(8)));
typedef float  f32x4  __attribute__((ext_vector_type(4)));
typedef unsigned int u32x4 __attribute__((ext_vector_type(4)));

static __device__ __forceinline__ ushort f2bf(float v) {
    union { float f; unsigned u; } x; x.f = v;
    unsigned r = x.u + 0x7fff + ((x.u >> 16) & 1);   // RNE
    return (ushort)(r >> 16);
}
static __device__ __forceinline__ float sigmoid_fast(float x) {
    return 1.f / (1.f + __expf(-x));
}
static __device__ __forceinline__ float tanh_fast(float x) {
    float e = __expf(2.f * x);
    return 1.f - 2.f / (e + 1.f);
}

// ---------------------------------------------------------------------------
// Pack weights into MFMA B-fragment order (bf16), and sum biases.
// Main W frags: frag = qg*40 + kc*4 + p   (qg 0..9, kc 0..9 K-chunk, p gate i/f/g/o)
//   frag[lane] = 8 bf16 of W[row = p*160 + qg*16 + (lane&15)][k = kcL*32 + (lane>>4)*8 + j]
//   kc<5 -> W_ih (X part), kc>=5 -> W_hh (H part)
// Final W frags: frag = kc*8 + nt : row = nt*16+(lane&15), k<160 -> W_l (vs h), else W_r (vs hin)
// ---------------------------------------------------------------------------
__global__ void pack_kernel(const float* __restrict__ Wih, const float* __restrict__ Whh,
                            const float* __restrict__ bih, const float* __restrict__ bhh,
                            const float* __restrict__ Wl,  const float* __restrict__ Wr,
                            ushort* __restrict__ wfrag, ushort* __restrict__ wlrfrag,
                            float* __restrict__ bsum)
{
    int gid = blockIdx.x * 256 + threadIdx.x;
    if (gid < 400 * 64) {
        int frag = gid >> 6, lane = gid & 63;
        int p = frag & 3, kc = (frag >> 2) % 10, qg = frag / 40;
        int row = p * 160 + qg * 16 + (lane & 15);
        int quad = lane >> 4;
        const float* src; int k0;
        if (kc < 5) { src = Wih + row * 160; k0 = kc * 32 + quad * 8; }
        else        { src = Whh + row * 160; k0 = (kc - 5) * 32 + quad * 8; }
        ushort tmp[8];
        #pragma unroll
        for (int j = 0; j < 8; j++) tmp[j] = f2bf(src[k0 + j]);
        ((u32x4*)wfrag)[frag * 64 + lane] = *(const u32x4*)tmp;
    } else if (gid < 400 * 64 + 80 * 64) {
        int g2 = gid - 400 * 64;
        int frag = g2 >> 6, lane = g2 & 63;
        int nt = frag & 7, kc = frag >> 3;
        int row = nt * 16 + (lane & 15);
        int quad = lane >> 4;
        int k0 = kc * 32 + quad * 8;
        ushort tmp[8];
        #pragma unroll
        for (int j = 0; j < 8; j++) {
            int k = k0 + j;
            float v = (k < 160) ? Wl[row * 160 + k] : Wr[row * 160 + (k - 160)];
            tmp[j] = f2bf(v);
        }
        ((u32x4*)wlrfrag)[frag * 64 + lane] = *(const u32x4*)tmp;
    } else if (gid < 400 * 64 + 80 * 64 + 640) {
        int i = gid - (400 * 64 + 80 * 64);
        bsum[i] = bih[i] + bhh[i];
    }
}

// h_in = concat(x, emb[type]) as bf16 rows of 160 (320 B, 16B aligned)
__global__ void build_hin(const float* __restrict__ x, const int* __restrict__ tids,
                          const float* __restrict__ emb, ushort* __restrict__ hin)
{
    int i = blockIdx.x * 256 + threadIdx.x;
    if (i >= N_NODES * F_DIM) return;
    int n = i / F_DIM, d = i - n * F_DIM;
    float v = (d < IN_CH) ? x[n * IN_CH + d] : emb[tids[n] * TYPE_DIM + (d - IN_CH)];
    hin[i] = f2bf(v);
}

// ---------------------------------------------------------------------------
// Fused LSTM aggregation + SAGE linear.
// Template NRQ = number of 48-row wave groups. M = NRQ*48 nodes per block.
// Waves: wv = (qh * NRQ + rq): rq = 48-row slice, qh = 80-gate-col half.
// Single H LDS buffer: h_new is held in registers during the read phase and
// committed after a barrier (removes double-buffer -> bigger M per block).
// X tile gathered into LDS per step; weights streamed from L2 (reuse x M rows).
// ---------------------------------------------------------------------------
template <int NRQ>
__launch_bounds__(NRQ * 128, 2)
__global__ void lstm_sage_t(const ushort* __restrict__ hin, const int* __restrict__ edge_src,
                            const ushort* __restrict__ wfrag, const float* __restrict__ bsum,
                            const ushort* __restrict__ wlrfrag, const float* __restrict__ bl,
                            float* __restrict__ out)
{
    constexpr int M  = NRQ * 48;
    constexpr int BT = NRQ * 128;
    extern __shared__ ushort lds[];
    ushort* Xb = lds;              // M * LS
    ushort* Hb = lds + M * LS;     // M * LS

    const int tid  = threadIdx.x;
    const int lane = tid & 63;
    const int wv   = tid >> 6;
    const int rq   = wv & (NRQ - 1);
    const int qh   = wv / NRQ;
    const int col  = lane & 15, quad = lane >> 4;
    const int nb   = blockIdx.x * M;
    const int rowbase = rq * 48;

    float bI[5], bF[5], bG[5], bO[5];
    #pragma unroll
    for (int q = 0; q < 5; q++) {
        int d = (qh * 5 + q) * 16 + col;
        bI[q] = bsum[d]; bF[q] = bsum[160 + d]; bG[q] = bsum[320 + d]; bO[q] = bsum[480 + d];
    }

    for (int i = tid; i < M * LS; i += BT) Hb[i] = 0;   // h0 = 0

    float c_st[5][3][4];
    #pragma unroll
    for (int q = 0; q < 5; q++)
        #pragma unroll
        for (int m = 0; m < 3; m++)
            #pragma unroll
            for (int r = 0; r < 4; r++) c_st[q][m][r] = 0.f;

    unsigned hn[5][3][2];   // packed bf16 h_new, committed post-barrier

    const int aoff = (rowbase + col) * LS + quad * 8;   // A-frag base (ushorts)

    #pragma unroll 1
    for (int t = 0; t < NSTEP; t++) {
        // gather X_t = h_in[src[node, t]] into Xb (nt: don't pollute L2)
        for (int i = tid; i < M * 20; i += BT) {
            int row = i / 20, seg = i - row * 20;
            int node = nb + row;
            int s = (node < N_NODES) ? edge_src[node * DEG + t] : 0;
            u32x4 v = __builtin_nontemporal_load((const u32x4*)(hin + s * F_DIM) + seg);
            *((u32x4*)(Xb + row * LS) + seg) = v;
        }
        __syncthreads();   // Xb ready; Hb writes of t-1 ready

        #pragma unroll
        for (int q = 0; q < 5; q++) {
            const int qg = qh * 5 + q;
            f32x4 acc[3][4];
            #pragma unroll
            for (int m = 0; m < 3; m++)
                #pragma unroll
                for (int p = 0; p < 4; p++) acc[m][p] = (f32x4){0.f, 0.f, 0.f, 0.f};

            const u32x4* wq = (const u32x4*)wfrag + qg * 40 * 64 + lane;
            #pragma unroll
            for (int kc = 0; kc < 10; kc++) {
                bf16x8 bfr[4];
                #pragma unroll
                for (int p = 0; p < 4; p++) {
                    u32x4 u = wq[(kc * 4 + p) * 64];
                    bfr[p] = *(const bf16x8*)&u;
                }
                const ushort* ab = (kc < 5) ? (Xb + kc * 32) : (Hb + (kc - 5) * 32);
                bf16x8 afr[3];
                #pragma unroll
                for (int m = 0; m < 3; m++)
                    afr[m] = *(const bf16x8*)(ab + aoff + m * (16 * LS));
                #pragma unroll
                for (int m = 0; m < 3; m++)
                    #pragma unroll
                    for (int p = 0; p < 4; p++)
                        acc[m][p] = __builtin_amdgcn_mfma_f32_16x16x32_bf16(
                            afr[m], bfr[p], acc[m][p], 0, 0, 0);
            }
            // LSTM elementwise (D-layout: node row = quad*4 + r)
            #pragma unroll
            for (int m = 0; m < 3; m++) {
                #pragma unroll
                for (int k = 0; k < 2; k++) {
                    unsigned pk = 0;
                    #pragma unroll
                    for (int h2 = 0; h2 < 2; h2++) {
                        int r = 2 * k + h2;
                        float gi = acc[m][0][r] + bI[q];
                        float gf = acc[m][1][r] + bF[q];
                        float gg = acc[m][2][r] + bG[q];
                        float go = acc[m][3][r] + bO[q];
                        float c  = sigmoid_fast(gf) * c_st[q][m][r] + sigmoid_fast(gi) * tanh_fast(gg);
                        c_st[q][m][r] = c;
                        float h  = sigmoid_fast(go) * tanh_fast(c);
                        pk |= ((unsigned)f2bf(h)) << (16 * h2);
                    }
                    hn[q][m][k] = pk;
                }
            }
        }
        __syncthreads();   // all reads of Hb done -> safe to overwrite

        #pragma unroll
        for (int q = 0; q < 5; q++) {
            #pragma unroll
            for (int m = 0; m < 3; m++) {
                #pragma unroll
                for (int k = 0; k < 2; k++) {
                    int row0 = rowbase + m * 16 + quad * 4 + 2 * k;
                    int a = row0 * LS + (qh * 5 + q) * 16 + col;
                    unsigned pk = hn[q][m][k];
                    Hb[a]      = (ushort)pk;
                    Hb[a + LS] = (ushort)(pk >> 16);
                }
            }
        }
    }

    // stage own h_in rows into Xb for lin_r
    for (int i = tid; i < M * 20; i += BT) {
        int row = i / 20, seg = i - row * 20;
        int node = nb + row;
        int s = (node < N_NODES) ? node : 0;
        u32x4 v = __builtin_nontemporal_load((const u32x4*)(hin + s * F_DIM) + seg);
        *((u32x4*)(Xb + row * LS) + seg) = v;
    }
    __syncthreads();

    // out = relu([h_last | h_in] @ [W_l | W_r]^T + b_l)
    f32x4 acc[3][4];
    #pragma unroll
    for (int m = 0; m < 3; m++)
        #pragma unroll
        for (int p = 0; p < 4; p++) acc[m][p] = (f32x4){0.f, 0.f, 0.f, 0.f};

    const u32x4* wq2 = (const u32x4*)wlrfrag + lane;
    #pragma unroll
    for (int kc = 0; kc < 10; kc++) {
        bf16x8 bfr[4];
        #pragma unroll
        for (int p = 0; p < 4; p++) {
            u32x4 u = wq2[(kc * 8 + qh * 4 + p) * 64];
            bfr[p] = *(const bf16x8*)&u;
        }
        const ushort* ab = (kc < 5) ? (Hb + kc * 32) : (Xb + (kc - 5) * 32);
        bf16x8 afr[3];
        #pragma unroll
        for (int m = 0; m < 3; m++)
            afr[m] = *(const bf16x8*)(ab + aoff + m * (16 * LS));
        #pragma unroll
        for (int m = 0; m < 3; m++)
            #pragma unroll
            for (int p = 0; p < 4; p++)
                acc[m][p] = __builtin_amdgcn_mfma_f32_16x16x32_bf16(
                    afr[m], bfr[p], acc[m][p], 0, 0, 0);
    }
    #pragma unroll
    for (int p = 0; p < 4; p++) {
        int ocol = qh * 64 + p * 16 + col;
        float bb = bl[ocol];
        #pragma unroll
        for (int m = 0; m < 3; m++) {
            int rowb = nb + rowbase + m * 16 + quad * 4;
            #pragma unroll
            for (int r = 0; r < 4; r++) {
                int node = rowb + r;
                if (node < N_NODES) {
                    float v = acc[m][p][r] + bb;
                    __builtin_nontemporal_store(v > 0.f ? v : 0.f, &out[node * OUT_CH + ocol]);
                }
            }
        }
    }
}

extern "C" void kernel_launch(void* const* d_in, const int* in_sizes, int n_in,
                              void* d_out, int out_size, void* d_ws, size_t ws_size,
                              hipStream_t stream)
{
    const float* x      = (const float*)d_in[0];
    const int*   tids   = (const int*)  d_in[1];
    const int*   esrc   = (const int*)  d_in[2];   // edge_index[0] = src (dst sorted, DEG each)
    const float* emb    = (const float*)d_in[3];
    const float* Wih    = (const float*)d_in[4];
    const float* Whh    = (const float*)d_in[5];
    const float* bih    = (const float*)d_in[6];
    const float* bhh    = (const float*)d_in[7];
    const float* Wl     = (const float*)d_in[8];
    const float* blin   = (const float*)d_in[9];
    const float* Wr     = (const float*)d_in[10];
    float* out = (float*)d_out;

    char* ws = (char*)d_ws;
    ushort* hin     = (ushort*)ws;                         // 16,000,000 B
    ushort* wfrag   = (ushort*)(ws + 16000000);            // 409,600 B
    ushort* wlrfrag = (ushort*)(ws + 16000000 + 409600);   // 81,920 B
    float*  bsum    = (float*) (ws + 16000000 + 409600 + 81920); // 2,560 B

    hipLaunchKernelGGL(pack_kernel, dim3(123), dim3(256), 0, stream,
                       Wih, Whh, bih, bhh, Wl, Wr, wfrag, wlrfrag, bsum);
    hipLaunchKernelGGL(build_hin, dim3((N_NODES * F_DIM + 255) / 256), dim3(256), 0, stream,
                       x, tids, emb, hin);

    // BIG config: M=192, 129KB dynamic LDS (needs >64KB/WG support). Probe
    // deterministically each call; fall back to M=96 / 64.5KB if rejected.
    const int bigShmem  = 2 * 192 * LS * (int)sizeof(ushort);  // 129024
    const int safeShmem = 2 * 96  * LS * (int)sizeof(ushort);  // 64512

    (void)hipFuncSetAttribute((const void*)lstm_sage_t<4>,
                              hipFuncAttributeMaxDynamicSharedMemorySize, bigShmem);
    hipFuncAttributes fa;
    bool bigOk = (hipFuncGetAttributes(&fa, (const void*)lstm_sage_t<4>) == hipSuccess) &&
                 (fa.maxDynamicSharedSizeBytes >= bigShmem);

    if (bigOk) {
        hipLaunchKernelGGL((lstm_sage_t<4>), dim3((N_NODES + 191) / 192), dim3(512),
                           bigShmem, stream, hin, esrc, wfrag, bsum, wlrfrag, blin, out);
    } else {
        hipLaunchKernelGGL((lstm_sage_t<2>), dim3((N_NODES + 95) / 96), dim3(256),
                           safeShmem, stream, hin, esrc, wfrag, bsum, wlrfrag, blin, out);
    }
}

// Round 5
// 1921.401 us; speedup vs baseline: 1.7874x; 1.7874x over previous
//
#include <hip/hip_runtime.h>
#include <hip/hip_bf16.h>

#define N_NODES 50000
#define DEG     16
#define IN_CH   128
#define TYPE_DIM 32
#define F_DIM   160      // = IN_CH + TYPE_DIM
#define H_DIM   160
#define OUT_CH  128
#define NSTEP   16       // = DEG timesteps
#define LS      168      // LDS row stride in ushorts (16B-aligned)

typedef short  bf16x8 __attribute__((ext_vector_type(8)));
typedef float  f32x4  __attribute__((ext_vector_type(4)));
typedef unsigned int u32x4 __attribute__((ext_vector_type(4)));

// ---------------------------------------------------------------------------
// Workspace relocated from d_ws to __device__ globals: R1-R4 showed a 400KB
// hot weight set missing L2 at ~50% (FETCH ~4.5GB) — hypothesis: d_ws memory
// is mapped uncached/streaming. Module globals are ordinary cached VRAM.
// All are fully rewritten by pack/build kernels every call.
// ---------------------------------------------------------------------------
__device__ ushort g_hin[N_NODES * F_DIM];       // 16,000,000 B
__device__ ushort g_wfrag[400 * 64 * 8];        // 409,600 B
__device__ ushort g_wlrfrag[80 * 64 * 8];       // 81,920 B
__device__ float  g_bsum[4 * H_DIM];            // 2,560 B

static __device__ __forceinline__ ushort f2bf(float v) {
    union { float f; unsigned u; } x; x.f = v;
    unsigned r = x.u + 0x7fff + ((x.u >> 16) & 1);   // RNE
    return (ushort)(r >> 16);
}
static __device__ __forceinline__ float sigmoid_fast(float x) {
    return 1.f / (1.f + __expf(-x));
}
static __device__ __forceinline__ float tanh_fast(float x) {
    float e = __expf(2.f * x);
    return 1.f - 2.f / (e + 1.f);
}

// ---------------------------------------------------------------------------
// Pack weights into MFMA B-fragment order (bf16), and sum biases.
// Main W frags: frag = qg*40 + kc*4 + p   (qg 0..9, kc 0..9 K-chunk, p gate i/f/g/o)
//   frag[lane] = 8 bf16 of W[row = p*160 + qg*16 + (lane&15)][k = kcL*32 + (lane>>4)*8 + j]
//   kc<5 -> W_ih (X part), kc>=5 -> W_hh (H part)
// Final W frags: frag = kc*8 + nt : row = nt*16+(lane&15), k<160 -> W_l, else W_r
// ---------------------------------------------------------------------------
__global__ void pack_kernel(const float* __restrict__ Wih, const float* __restrict__ Whh,
                            const float* __restrict__ bih, const float* __restrict__ bhh,
                            const float* __restrict__ Wl,  const float* __restrict__ Wr)
{
    int gid = blockIdx.x * 256 + threadIdx.x;
    if (gid < 400 * 64) {
        int frag = gid >> 6, lane = gid & 63;
        int p = frag & 3, kc = (frag >> 2) % 10, qg = frag / 40;
        int row = p * 160 + qg * 16 + (lane & 15);
        int quad = lane >> 4;
        const float* src; int k0;
        if (kc < 5) { src = Wih + row * 160; k0 = kc * 32 + quad * 8; }
        else        { src = Whh + row * 160; k0 = (kc - 5) * 32 + quad * 8; }
        ushort tmp[8];
        #pragma unroll
        for (int j = 0; j < 8; j++) tmp[j] = f2bf(src[k0 + j]);
        ((u32x4*)g_wfrag)[frag * 64 + lane] = *(const u32x4*)tmp;
    } else if (gid < 400 * 64 + 80 * 64) {
        int g2 = gid - 400 * 64;
        int frag = g2 >> 6, lane = g2 & 63;
        int nt = frag & 7, kc = frag >> 3;
        int row = nt * 16 + (lane & 15);
        int quad = lane >> 4;
        int k0 = kc * 32 + quad * 8;
        ushort tmp[8];
        #pragma unroll
        for (int j = 0; j < 8; j++) {
            int k = k0 + j;
            float v = (k < 160) ? Wl[row * 160 + k] : Wr[row * 160 + (k - 160)];
            tmp[j] = f2bf(v);
        }
        ((u32x4*)g_wlrfrag)[frag * 64 + lane] = *(const u32x4*)tmp;
    } else if (gid < 400 * 64 + 80 * 64 + 640) {
        int i = gid - (400 * 64 + 80 * 64);
        g_bsum[i] = bih[i] + bhh[i];
    }
}

// h_in = concat(x, emb[type]) as bf16 rows of 160 (320 B, 16B aligned)
__global__ void build_hin(const float* __restrict__ x, const int* __restrict__ tids,
                          const float* __restrict__ emb)
{
    int i = blockIdx.x * 256 + threadIdx.x;
    if (i >= N_NODES * F_DIM) return;
    int n = i / F_DIM, d = i - n * F_DIM;
    float v = (d < IN_CH) ? x[n * IN_CH + d] : emb[tids[n] * TYPE_DIM + (d - IN_CH)];
    g_hin[i] = f2bf(v);
}

// ---------------------------------------------------------------------------
// Fused LSTM-aggregation + SAGE linear. Block = 64 nodes, 4 waves.
// wave = (mHalf = wv&1 : 32-node half, qgHalf = wv>>1 : 5 of 10 h-dim groups)
// ---------------------------------------------------------------------------
__launch_bounds__(256, 2)
__global__ void lstm_sage(const int* __restrict__ edge_src,
                          const float* __restrict__ bl,
                          float* __restrict__ out)
{
    __shared__ ushort Xb[64 * LS];
    __shared__ ushort Hb[2][64 * LS];

    const int tid  = threadIdx.x;
    const int lane = tid & 63;
    const int wv   = tid >> 6;
    const int mHalf = wv & 1, qgHalf = wv >> 1;
    const int col = lane & 15, quad = lane >> 4;
    const int nb = blockIdx.x * 64;

    float bI[5], bF[5], bG[5], bO[5];
    #pragma unroll
    for (int q = 0; q < 5; q++) {
        int d = (qgHalf * 5 + q) * 16 + col;
        bI[q] = g_bsum[d]; bF[q] = g_bsum[160 + d];
        bG[q] = g_bsum[320 + d]; bO[q] = g_bsum[480 + d];
    }

    for (int i = tid; i < 64 * LS; i += 256) Hb[0][i] = 0;   // h0 = 0

    float c_st[5][2][4];
    #pragma unroll
    for (int q = 0; q < 5; q++)
        #pragma unroll
        for (int m = 0; m < 2; m++)
            #pragma unroll
            for (int r = 0; r < 4; r++) c_st[q][m][r] = 0.f;

    const int grow = tid >> 2;     // gather: 4 threads per row
    const int gpart = tid & 3;

    for (int t = 0; t < NSTEP; t++) {
        __syncthreads();           // Xb free, previous Hn writes visible
        {   // gather X_t = h_in[src[node, t]]
            int node = nb + grow;
            int s = (node < N_NODES) ? edge_src[node * DEG + t] : 0;
            const u32x4* sp = (const u32x4*)(g_hin + s * F_DIM);
            u32x4* dp = (u32x4*)(Xb + grow * LS);
            #pragma unroll
            for (int j = 0; j < 5; j++) dp[gpart + j * 4] = sp[gpart + j * 4];
        }
        __syncthreads();

        const ushort* Hc = Hb[t & 1];
        ushort*       Hn = Hb[(t + 1) & 1];

        #pragma unroll
        for (int q = 0; q < 5; q++) {
            int qg = qgHalf * 5 + q;
            f32x4 acc[2][4];
            #pragma unroll
            for (int m = 0; m < 2; m++)
                #pragma unroll
                for (int p = 0; p < 4; p++) acc[m][p] = (f32x4){0.f, 0.f, 0.f, 0.f};

            const u32x4* wq = (const u32x4*)g_wfrag + qg * 40 * 64 + lane;
            #pragma unroll
            for (int kc = 0; kc < 10; kc++) {
                bf16x8 bfr[4];
                #pragma unroll
                for (int p = 0; p < 4; p++) {
                    u32x4 u = wq[(kc * 4 + p) * 64];
                    bfr[p] = *(const bf16x8*)&u;
                }
                const ushort* abase = (kc < 5) ? (Xb + kc * 32) : (Hc + (kc - 5) * 32);
                bf16x8 afr[2];
                #pragma unroll
                for (int m = 0; m < 2; m++) {
                    int row = mHalf * 32 + m * 16 + col;
                    afr[m] = *(const bf16x8*)(abase + row * LS + quad * 8);
                }
                #pragma unroll
                for (int m = 0; m < 2; m++)
                    #pragma unroll
                    for (int p = 0; p < 4; p++)
                        acc[m][p] = __builtin_amdgcn_mfma_f32_16x16x32_bf16(
                            afr[m], bfr[p], acc[m][p], 0, 0, 0);
            }
            // LSTM elementwise: D-layout row = quad*4 + r (node), col (dim)
            #pragma unroll
            for (int m = 0; m < 2; m++) {
                int rowb = mHalf * 32 + m * 16 + quad * 4;
                #pragma unroll
                for (int r = 0; r < 4; r++) {
                    float gi = acc[m][0][r] + bI[q];
                    float gf = acc[m][1][r] + bF[q];
                    float gg = acc[m][2][r] + bG[q];
                    float go = acc[m][3][r] + bO[q];
                    float c  = sigmoid_fast(gf) * c_st[q][m][r] + sigmoid_fast(gi) * tanh_fast(gg);
                    c_st[q][m][r] = c;
                    float h  = sigmoid_fast(go) * tanh_fast(c);
                    Hn[(rowb + r) * LS + qg * 16 + col] = f2bf(h);
                }
            }
        }
    }

    __syncthreads();
    {   // stage own h_in rows into Xb for lin_r
        int node = nb + grow;
        int s = (node < N_NODES) ? node : 0;
        const u32x4* sp = (const u32x4*)(g_hin + s * F_DIM);
        u32x4* dp = (u32x4*)(Xb + grow * LS);
        #pragma unroll
        for (int j = 0; j < 5; j++) dp[gpart + j * 4] = sp[gpart + j * 4];
    }
    __syncthreads();

    const ushort* Hlast = Hb[0];   // (15+1)&1 == 0
    // out = relu([Hlast | h_in] @ [W_l | W_r]^T + b_l); wave = (mHalf, nHalf=qgHalf)
    f32x4 acc[2][4];
    #pragma unroll
    for (int m = 0; m < 2; m++)
        #pragma unroll
        for (int p = 0; p < 4; p++) acc[m][p] = (f32x4){0.f, 0.f, 0.f, 0.f};

    const u32x4* wq = (const u32x4*)g_wlrfrag + lane;
    #pragma unroll
    for (int kc = 0; kc < 10; kc++) {
        bf16x8 bfr[4];
        #pragma unroll
        for (int p = 0; p < 4; p++) {
            u32x4 u = wq[(kc * 8 + qgHalf * 4 + p) * 64];
            bfr[p] = *(const bf16x8*)&u;
        }
        const ushort* abase = (kc < 5) ? (Hlast + kc * 32) : (Xb + (kc - 5) * 32);
        bf16x8 afr[2];
        #pragma unroll
        for (int m = 0; m < 2; m++) {
            int row = mHalf * 32 + m * 16 + col;
            afr[m] = *(const bf16x8*)(abase + row * LS + quad * 8);
        }
        #pragma unroll
        for (int m = 0; m < 2; m++)
            #pragma unroll
            for (int p = 0; p < 4; p++)
                acc[m][p] = __builtin_amdgcn_mfma_f32_16x16x32_bf16(
                    afr[m], bfr[p], acc[m][p], 0, 0, 0);
    }
    #pragma unroll
    for (int p = 0; p < 4; p++) {
        int ocol = qgHalf * 64 + p * 16 + col;
        float bb = bl[ocol];
        #pragma unroll
        for (int m = 0; m < 2; m++) {
            int rowb = nb + mHalf * 32 + m * 16 + quad * 4;
            #pragma unroll
            for (int r = 0; r < 4; r++) {
                int node = rowb + r;
                if (node < N_NODES) {
                    float v = acc[m][p][r] + bb;
                    out[node * OUT_CH + ocol] = v > 0.f ? v : 0.f;
                }
            }
        }
    }
}

extern "C" void kernel_launch(void* const* d_in, const int* in_sizes, int n_in,
                              void* d_out, int out_size, void* d_ws, size_t ws_size,
                              hipStream_t stream)
{
    const float* x      = (const float*)d_in[0];
    const int*   tids   = (const int*)  d_in[1];
    const int*   esrc   = (const int*)  d_in[2];   // edge_index[0] = src (dst sorted, DEG each)
    const float* emb    = (const float*)d_in[3];
    const float* Wih    = (const float*)d_in[4];
    const float* Whh    = (const float*)d_in[5];
    const float* bih    = (const float*)d_in[6];
    const float* bhh    = (const float*)d_in[7];
    const float* Wl     = (const float*)d_in[8];
    const float* blin   = (const float*)d_in[9];
    const float* Wr     = (const float*)d_in[10];
    float* out = (float*)d_out;

    hipLaunchKernelGGL(pack_kernel, dim3(123), dim3(256), 0, stream,
                       Wih, Whh, bih, bhh, Wl, Wr);
    hipLaunchKernelGGL(build_hin, dim3((N_NODES * F_DIM + 255) / 256), dim3(256), 0, stream,
                       x, tids, emb);
    hipLaunchKernelGGL(lstm_sage, dim3((N_NODES + 63) / 64), dim3(256), 0, stream,
                       esrc, blin, out);
}